// Round 1
// baseline (79.090 us; speedup 1.0000x reference)
//
#include <hip/hip_runtime.h>
#include <math.h>

#define NQ   10
#define DIMQ 1024
#define BATCH_ROWS 16384

// butterfly on a pair (a = bit0 element, b = bit1 element):
//   a' = a + i*b ; b' = b + i*a      (global 1/sqrt2 scales folded into diagonals)
#define BFLY(ar, ai, br, bi) do {            \
    float _tr = (ar), _ti = (ai);            \
    (ar) = (ar) - (bi); (ai) = (ai) + (br);  \
    (br) = (br) - _ti;  (bi) = (bi) + _tr;   \
} while (0)

// ---------------------------------------------------------------------------
// Precompute the three Kronecker diagonals into ws (float2[3*1024]).
//   ws[0..1023]      = exp(i * phase_in(e))                 (alphas/betas)
//   ws[1024..2047]   = exp(i * phase_theta(e)) / 32         (thetas vs 0)
//   ws[2048..3071]   = exp(i * phase_phi(e))   / 32         (phis vs 0)
// Bit p (LSB) of element index e corresponds to qubit q = 9-p.
// ---------------------------------------------------------------------------
__global__ void qdiag_precompute(const float* __restrict__ alphas,
                                 const float* __restrict__ betas,
                                 const float* __restrict__ thetas,
                                 const float* __restrict__ phis,
                                 float2* __restrict__ ws) {
    const int e = threadIdx.x;
    float pin = 0.f, pt = 0.f, pp = 0.f;
#pragma unroll
    for (int p = 0; p < NQ; ++p) {
        const int q = NQ - 1 - p;
        if ((e >> p) & 1) {
            pin += betas[q];
        } else {
            pin += alphas[q];
            pt  += thetas[q];
            pp  += phis[q];
        }
    }
    float s, c;
    sincosf(pin, &s, &c);
    ws[e] = make_float2(c, s);
    sincosf(pt, &s, &c);
    ws[DIMQ + e] = make_float2(c * 0.03125f, s * 0.03125f);
    sincosf(pp, &s, &c);
    ws[2 * DIMQ + e] = make_float2(c * 0.03125f, s * 0.03125f);
}

// ---------------------------------------------------------------------------
// Helpers operating on one wave's 16-complex register tile.
// element index: e = j*256 + lane*4 + l
// ---------------------------------------------------------------------------
__device__ __forceinline__ void diag_apply_ws(float re[4][4], float im[4][4],
                                              int lane, const float2* __restrict__ dg) {
#pragma unroll
    for (int j = 0; j < 4; ++j) {
        const float4* dp = (const float4*)(dg + j * 256 + lane * 4);
        const float4 d01 = dp[0];   // (c0,s0,c1,s1)
        const float4 d23 = dp[1];   // (c2,s2,c3,s3)
        float dc[4] = {d01.x, d01.z, d23.x, d23.z};
        float ds[4] = {d01.y, d01.w, d23.y, d23.w};
#pragma unroll
        for (int l = 0; l < 4; ++l) {
            const float r = re[j][l], i = im[j][l];
            re[j][l] = r * dc[l] - i * ds[l];
            im[j][l] = r * ds[l] + i * dc[l];
        }
    }
}

// slow fallback: compute diag per element (only used if ws_size is too small)
__device__ __forceinline__ void diag_apply_inline(float re[4][4], float im[4][4], int lane,
                                                  const float* __restrict__ p0,
                                                  const float* __restrict__ p1,
                                                  float scale) {
#pragma unroll
    for (int j = 0; j < 4; ++j)
#pragma unroll
        for (int l = 0; l < 4; ++l) {
            const int e = j * 256 + lane * 4 + l;
            float ph = 0.f;
#pragma unroll
            for (int p = 0; p < NQ; ++p) {
                const int q = NQ - 1 - p;
                ph += ((e >> p) & 1) ? (p1 ? p1[q] : 0.f) : p0[q];
            }
            float s, c;
            sincosf(ph, &s, &c);
            c *= scale; s *= scale;
            const float r = re[j][l], i = im[j][l];
            re[j][l] = r * c - i * s;
            im[j][l] = r * s + i * c;
        }
}

__device__ __forceinline__ void bs_transform(float re[4][4], float im[4][4]) {
    // bit 0 (l ^ 1)
#pragma unroll
    for (int j = 0; j < 4; ++j) {
        BFLY(re[j][0], im[j][0], re[j][1], im[j][1]);
        BFLY(re[j][2], im[j][2], re[j][3], im[j][3]);
    }
    // bit 1 (l ^ 2)
#pragma unroll
    for (int j = 0; j < 4; ++j) {
        BFLY(re[j][0], im[j][0], re[j][2], im[j][2]);
        BFLY(re[j][1], im[j][1], re[j][3], im[j][3]);
    }
    // bits 2..7: cross-lane, masks 1..32. new = mine + i*partner (symmetric).
#pragma unroll
    for (int s = 0; s < 6; ++s) {
        const int m = 1 << s;
#pragma unroll
        for (int j = 0; j < 4; ++j)
#pragma unroll
            for (int l = 0; l < 4; ++l) {
                const float pr = __shfl_xor(re[j][l], m, 64);
                const float pi = __shfl_xor(im[j][l], m, 64);
                re[j][l] -= pi;
                im[j][l] += pr;
            }
    }
    // bit 8 (j ^ 1)
#pragma unroll
    for (int l = 0; l < 4; ++l) {
        BFLY(re[0][l], im[0][l], re[1][l], im[1][l]);
        BFLY(re[2][l], im[2][l], re[3][l], im[3][l]);
    }
    // bit 9 (j ^ 2)
#pragma unroll
    for (int l = 0; l < 4; ++l) {
        BFLY(re[0][l], im[0][l], re[2][l], im[2][l]);
        BFLY(re[1][l], im[1][l], re[3][l], im[3][l]);
    }
}

// ---------------------------------------------------------------------------
// Main kernel: one wave per batch row. x/out layout: (B, 2, 1024) f32.
// ---------------------------------------------------------------------------
template <bool USE_WS>
__global__ __launch_bounds__(256)
void qlayer_kernel(const float* __restrict__ x,
                   const float2* __restrict__ diag,
                   const float* __restrict__ alphas, const float* __restrict__ betas,
                   const float* __restrict__ thetas, const float* __restrict__ phis,
                   float* __restrict__ out) {
    const int lane = threadIdx.x & 63;
    const int wv   = threadIdx.x >> 6;
    const int row  = blockIdx.x * 4 + wv;

    const float* __restrict__ xr = x + (size_t)row * (2 * DIMQ);
    float* __restrict__ orow     = out + (size_t)row * (2 * DIMQ);

    float re[4][4], im[4][4];
#pragma unroll
    for (int j = 0; j < 4; ++j) {
        const float4 r4 = *(const float4*)(xr + j * 256 + lane * 4);
        const float4 i4 = *(const float4*)(xr + DIMQ + j * 256 + lane * 4);
        re[j][0] = r4.x; re[j][1] = r4.y; re[j][2] = r4.z; re[j][3] = r4.w;
        im[j][0] = i4.x; im[j][1] = i4.y; im[j][2] = i4.z; im[j][3] = i4.w;
    }

    if (USE_WS) diag_apply_ws(re, im, lane, diag);
    else        diag_apply_inline(re, im, lane, alphas, betas, 1.0f);

    bs_transform(re, im);

    if (USE_WS) diag_apply_ws(re, im, lane, diag + DIMQ);
    else        diag_apply_inline(re, im, lane, thetas, nullptr, 0.03125f);

    bs_transform(re, im);

    if (USE_WS) diag_apply_ws(re, im, lane, diag + 2 * DIMQ);
    else        diag_apply_inline(re, im, lane, phis, nullptr, 0.03125f);

#pragma unroll
    for (int j = 0; j < 4; ++j) {
        float4 r4 = make_float4(re[j][0], re[j][1], re[j][2], re[j][3]);
        float4 i4 = make_float4(im[j][0], im[j][1], im[j][2], im[j][3]);
        *(float4*)(orow + j * 256 + lane * 4) = r4;
        *(float4*)(orow + DIMQ + j * 256 + lane * 4) = i4;
    }
}

extern "C" void kernel_launch(void* const* d_in, const int* in_sizes, int n_in,
                              void* d_out, int out_size, void* d_ws, size_t ws_size,
                              hipStream_t stream) {
    const float* x      = (const float*)d_in[0];
    const float* alphas = (const float*)d_in[1];
    const float* betas  = (const float*)d_in[2];
    const float* thetas = (const float*)d_in[3];
    const float* phis   = (const float*)d_in[4];
    float* out = (float*)d_out;

    const int blocks = BATCH_ROWS / 4;  // 4 waves (rows) per 256-thread block

    if (ws_size >= 3 * DIMQ * sizeof(float2)) {
        float2* ws = (float2*)d_ws;
        qdiag_precompute<<<1, DIMQ, 0, stream>>>(alphas, betas, thetas, phis, ws);
        qlayer_kernel<true><<<blocks, 256, 0, stream>>>(x, ws, alphas, betas, thetas, phis, out);
    } else {
        qlayer_kernel<false><<<blocks, 256, 0, stream>>>(x, nullptr, alphas, betas, thetas, phis, out);
    }
}

// Round 2
// 53.244 us; speedup vs baseline: 1.4854x; 1.4854x over previous
//
#include <hip/hip_runtime.h>
#include <math.h>

#define NQ   10
#define DIMQ 1024
#define BATCH_ROWS 16384

typedef unsigned uv2 __attribute__((ext_vector_type(2)));

#if __has_builtin(__builtin_amdgcn_permlane32_swap)
#define HAS_PLS32 1
#else
#define HAS_PLS32 0
#endif
#if __has_builtin(__builtin_amdgcn_permlane16_swap)
#define HAS_PLS16 1
#else
#define HAS_PLS16 0
#endif

// butterfly on a local register pair: a' = a + i*b ; b' = b + i*a
#define BFLY(ar, ai, br, bi) do {            \
    float _tr = (ar), _ti = (ai);            \
    (ar) = (ar) - (bi); (ai) = (ai) + (br);  \
    (br) = (br) - _ti;  (bi) = (bi) + _tr;   \
} while (0)

// ---------------------------------------------------------------------------
// Diagonal precompute (3 x 1024 float2) into ws.
// ---------------------------------------------------------------------------
__global__ void qdiag_precompute(const float* __restrict__ alphas,
                                 const float* __restrict__ betas,
                                 const float* __restrict__ thetas,
                                 const float* __restrict__ phis,
                                 float2* __restrict__ ws) {
    const int e = threadIdx.x;
    float pin = 0.f, pt = 0.f, pp = 0.f;
#pragma unroll
    for (int p = 0; p < NQ; ++p) {
        const int q = NQ - 1 - p;
        if ((e >> p) & 1) {
            pin += betas[q];
        } else {
            pin += alphas[q];
            pt  += thetas[q];
            pp  += phis[q];
        }
    }
    float s, c;
    sincosf(pin, &s, &c);
    ws[e] = make_float2(c, s);
    sincosf(pt, &s, &c);
    ws[DIMQ + e] = make_float2(c * 0.03125f, s * 0.03125f);
    sincosf(pp, &s, &c);
    ws[2 * DIMQ + e] = make_float2(c * 0.03125f, s * 0.03125f);
}

// ---------------------------------------------------------------------------
// Cross-lane primitives
// ---------------------------------------------------------------------------
template <int CTRL>
__device__ __forceinline__ float dpp_mov(float x) {
    return __int_as_float(
        __builtin_amdgcn_update_dpp(0, __float_as_int(x), CTRL, 0xF, 0xF, true));
}

template <int PAT>
__device__ __forceinline__ float ds_swz(float x) {
    return __int_as_float(__builtin_amdgcn_ds_swizzle(__float_as_int(x), PAT));
}

// quad_perm encodings: xor1 = [1,0,3,2] = 0xB1 ; xor2 = [2,3,0,1] = 0x4E
#define DPP_XOR1 0xB1
#define DPP_XOR2 0x4E
// ds_swizzle bitmode: offset = xor<<10 | 0x1F
#define SWZ_XOR4  0x101F
#define SWZ_XOR8  0x201F
#define SWZ_XOR16 0x401F

// permlane{16,32}_swap based butterfly on TWO complex values at once.
// (p,q) = S(f,g); A = p + i*q; B = q + i*p; (f',g') = S(A,B)
// Correct under both half-swap orientations provided the builtin returns
// (updated arg0, updated arg1) — verified at runtime by detect_pls{16,32}.
#if HAS_PLS32
__device__ __forceinline__ void pls32_bfly(float& fr, float& fi, float& gr, float& gi) {
    uv2 pr = __builtin_amdgcn_permlane32_swap(__float_as_uint(fr), __float_as_uint(gr), false, false);
    uv2 pi = __builtin_amdgcn_permlane32_swap(__float_as_uint(fi), __float_as_uint(gi), false, false);
    float Ar = __uint_as_float(pr.x) - __uint_as_float(pi.y);
    float Ai = __uint_as_float(pi.x) + __uint_as_float(pr.y);
    float Br = __uint_as_float(pr.y) - __uint_as_float(pi.x);
    float Bi = __uint_as_float(pi.y) + __uint_as_float(pr.x);
    uv2 rr = __builtin_amdgcn_permlane32_swap(__float_as_uint(Ar), __float_as_uint(Br), false, false);
    uv2 ri = __builtin_amdgcn_permlane32_swap(__float_as_uint(Ai), __float_as_uint(Bi), false, false);
    fr = __uint_as_float(rr.x); gr = __uint_as_float(rr.y);
    fi = __uint_as_float(ri.x); gi = __uint_as_float(ri.y);
}
#endif
#if HAS_PLS16
__device__ __forceinline__ void pls16_bfly(float& fr, float& fi, float& gr, float& gi) {
    uv2 pr = __builtin_amdgcn_permlane16_swap(__float_as_uint(fr), __float_as_uint(gr), false, false);
    uv2 pi = __builtin_amdgcn_permlane16_swap(__float_as_uint(fi), __float_as_uint(gi), false, false);
    float Ar = __uint_as_float(pr.x) - __uint_as_float(pi.y);
    float Ai = __uint_as_float(pi.x) + __uint_as_float(pr.y);
    float Br = __uint_as_float(pr.y) - __uint_as_float(pi.x);
    float Bi = __uint_as_float(pi.y) + __uint_as_float(pr.x);
    uv2 rr = __builtin_amdgcn_permlane16_swap(__float_as_uint(Ar), __float_as_uint(Br), false, false);
    uv2 ri = __builtin_amdgcn_permlane16_swap(__float_as_uint(Ai), __float_as_uint(Bi), false, false);
    fr = __uint_as_float(rr.x); gr = __uint_as_float(rr.y);
    fi = __uint_as_float(ri.x); gi = __uint_as_float(ri.y);
}
#endif

__device__ __forceinline__ bool detect_pls32(unsigned lane) {
#if HAS_PLS32
    uv2 r = __builtin_amdgcn_permlane32_swap(lane, 1000u + lane, false, false);
    const bool lo = lane < 32;
    unsigned ax = lo ? lane : (1000u + lane - 32u);
    unsigned ay = lo ? (lane + 32u) : (1000u + lane);
    unsigned bx = lo ? (1000u + lane + 32u) : lane;
    unsigned by = lo ? (1000u + lane) : (lane - 32u);
    bool ok = (r.x == ax && r.y == ay) || (r.x == bx && r.y == by);
    return __all(ok);
#else
    return false;
#endif
}

__device__ __forceinline__ bool detect_pls16(unsigned lane) {
#if HAS_PLS16
    uv2 r = __builtin_amdgcn_permlane16_swap(lane, 1000u + lane, false, false);
    const bool odd = (lane & 16u) != 0u;
    unsigned ax = odd ? (1000u + lane - 16u) : lane;
    unsigned ay = odd ? (1000u + lane) : (lane + 16u);
    unsigned bx = odd ? lane : (1000u + lane + 16u);
    unsigned by = odd ? (lane - 16u) : (1000u + lane);
    bool ok = (r.x == ax && r.y == ay) || (r.x == bx && r.y == by);
    return __all(ok);
#else
    return false;
#endif
}

// ---------------------------------------------------------------------------
// Diagonal application on the 16-complex register tile. e = j*256 + lane*4 + l
// ---------------------------------------------------------------------------
__device__ __forceinline__ void diag_apply_ws(float re[4][4], float im[4][4],
                                              int lane, const float2* __restrict__ dg) {
#pragma unroll
    for (int j = 0; j < 4; ++j) {
        const float4* dp = (const float4*)(dg + j * 256 + lane * 4);
        const float4 d01 = dp[0];
        const float4 d23 = dp[1];
        float dc[4] = {d01.x, d01.z, d23.x, d23.z};
        float ds[4] = {d01.y, d01.w, d23.y, d23.w};
#pragma unroll
        for (int l = 0; l < 4; ++l) {
            const float r = re[j][l], i = im[j][l];
            re[j][l] = r * dc[l] - i * ds[l];
            im[j][l] = r * ds[l] + i * dc[l];
        }
    }
}

__device__ __forceinline__ void diag_apply_inline(float re[4][4], float im[4][4], int lane,
                                                  const float* __restrict__ p0,
                                                  const float* __restrict__ p1,
                                                  float scale) {
#pragma unroll
    for (int j = 0; j < 4; ++j)
#pragma unroll
        for (int l = 0; l < 4; ++l) {
            const int e = j * 256 + lane * 4 + l;
            float ph = 0.f;
#pragma unroll
            for (int p = 0; p < NQ; ++p) {
                const int q = NQ - 1 - p;
                ph += ((e >> p) & 1) ? (p1 ? p1[q] : 0.f) : p0[q];
            }
            float s, c;
            sincosf(ph, &s, &c);
            c *= scale; s *= scale;
            const float r = re[j][l], i = im[j][l];
            re[j][l] = r * c - i * s;
            im[j][l] = r * s + i * c;
        }
}

// ---------------------------------------------------------------------------
// Beamsplitter transform. Stages (element bit -> mechanism):
//  bit0,bit1: register (l), bit2: DPP xor1, bit3: DPP xor2,
//  bit4: ds_swizzle xor4, bit5: ds_swizzle xor8,
//  bit6: permlane16_swap, bit7: permlane32_swap, bit8,bit9: register (j)
// ---------------------------------------------------------------------------
__device__ __forceinline__ void bs_transform(float re[4][4], float im[4][4],
                                             bool p16ok, bool p32ok) {
    // bit 0 (l ^ 1) and bit 1 (l ^ 2): register-local
#pragma unroll
    for (int j = 0; j < 4; ++j) {
        BFLY(re[j][0], im[j][0], re[j][1], im[j][1]);
        BFLY(re[j][2], im[j][2], re[j][3], im[j][3]);
    }
#pragma unroll
    for (int j = 0; j < 4; ++j) {
        BFLY(re[j][0], im[j][0], re[j][2], im[j][2]);
        BFLY(re[j][1], im[j][1], re[j][3], im[j][3]);
    }
    // lane mask 1: DPP quad_perm
#pragma unroll
    for (int j = 0; j < 4; ++j)
#pragma unroll
        for (int l = 0; l < 4; ++l) {
            const float pr = dpp_mov<DPP_XOR1>(re[j][l]);
            const float pi = dpp_mov<DPP_XOR1>(im[j][l]);
            re[j][l] -= pi; im[j][l] += pr;
        }
    // lane mask 2: DPP quad_perm
#pragma unroll
    for (int j = 0; j < 4; ++j)
#pragma unroll
        for (int l = 0; l < 4; ++l) {
            const float pr = dpp_mov<DPP_XOR2>(re[j][l]);
            const float pi = dpp_mov<DPP_XOR2>(im[j][l]);
            re[j][l] -= pi; im[j][l] += pr;
        }
    // lane mask 4: ds_swizzle
#pragma unroll
    for (int j = 0; j < 4; ++j)
#pragma unroll
        for (int l = 0; l < 4; ++l) {
            const float pr = ds_swz<SWZ_XOR4>(re[j][l]);
            const float pi = ds_swz<SWZ_XOR4>(im[j][l]);
            re[j][l] -= pi; im[j][l] += pr;
        }
    // lane mask 8: ds_swizzle
#pragma unroll
    for (int j = 0; j < 4; ++j)
#pragma unroll
        for (int l = 0; l < 4; ++l) {
            const float pr = ds_swz<SWZ_XOR8>(re[j][l]);
            const float pi = ds_swz<SWZ_XOR8>(im[j][l]);
            re[j][l] -= pi; im[j][l] += pr;
        }
    // lane mask 16: permlane16_swap (VALU) or swizzle fallback
#if HAS_PLS16
    if (p16ok) {
#pragma unroll
        for (int j = 0; j < 4; ++j) {
            pls16_bfly(re[j][0], im[j][0], re[j][1], im[j][1]);
            pls16_bfly(re[j][2], im[j][2], re[j][3], im[j][3]);
        }
    } else
#endif
    {
#pragma unroll
        for (int j = 0; j < 4; ++j)
#pragma unroll
            for (int l = 0; l < 4; ++l) {
                const float pr = ds_swz<SWZ_XOR16>(re[j][l]);
                const float pi = ds_swz<SWZ_XOR16>(im[j][l]);
                re[j][l] -= pi; im[j][l] += pr;
            }
    }
    // lane mask 32: permlane32_swap (VALU) or shfl fallback
#if HAS_PLS32
    if (p32ok) {
#pragma unroll
        for (int j = 0; j < 4; ++j) {
            pls32_bfly(re[j][0], im[j][0], re[j][1], im[j][1]);
            pls32_bfly(re[j][2], im[j][2], re[j][3], im[j][3]);
        }
    } else
#endif
    {
#pragma unroll
        for (int j = 0; j < 4; ++j)
#pragma unroll
            for (int l = 0; l < 4; ++l) {
                const float pr = __shfl_xor(re[j][l], 32, 64);
                const float pi = __shfl_xor(im[j][l], 32, 64);
                re[j][l] -= pi; im[j][l] += pr;
            }
    }
    // bit 8 (j ^ 1) and bit 9 (j ^ 2): register-local
#pragma unroll
    for (int l = 0; l < 4; ++l) {
        BFLY(re[0][l], im[0][l], re[1][l], im[1][l]);
        BFLY(re[2][l], im[2][l], re[3][l], im[3][l]);
    }
#pragma unroll
    for (int l = 0; l < 4; ++l) {
        BFLY(re[0][l], im[0][l], re[2][l], im[2][l]);
        BFLY(re[1][l], im[1][l], re[3][l], im[3][l]);
    }
}

// ---------------------------------------------------------------------------
// Main kernel: one wave per batch row. x/out layout: (B, 2, 1024) f32.
// ---------------------------------------------------------------------------
template <bool USE_WS>
__global__ __launch_bounds__(256)
void qlayer_kernel(const float* __restrict__ x,
                   const float2* __restrict__ diag,
                   const float* __restrict__ alphas, const float* __restrict__ betas,
                   const float* __restrict__ thetas, const float* __restrict__ phis,
                   float* __restrict__ out) {
    const int lane = threadIdx.x & 63;
    const int wv   = threadIdx.x >> 6;
    const int row  = blockIdx.x * 4 + wv;

    const bool p16ok = detect_pls16((unsigned)lane);
    const bool p32ok = detect_pls32((unsigned)lane);

    const float* __restrict__ xr = x + (size_t)row * (2 * DIMQ);
    float* __restrict__ orow     = out + (size_t)row * (2 * DIMQ);

    float re[4][4], im[4][4];
#pragma unroll
    for (int j = 0; j < 4; ++j) {
        const float4 r4 = *(const float4*)(xr + j * 256 + lane * 4);
        const float4 i4 = *(const float4*)(xr + DIMQ + j * 256 + lane * 4);
        re[j][0] = r4.x; re[j][1] = r4.y; re[j][2] = r4.z; re[j][3] = r4.w;
        im[j][0] = i4.x; im[j][1] = i4.y; im[j][2] = i4.z; im[j][3] = i4.w;
    }

    if (USE_WS) diag_apply_ws(re, im, lane, diag);
    else        diag_apply_inline(re, im, lane, alphas, betas, 1.0f);

    bs_transform(re, im, p16ok, p32ok);

    if (USE_WS) diag_apply_ws(re, im, lane, diag + DIMQ);
    else        diag_apply_inline(re, im, lane, thetas, nullptr, 0.03125f);

    bs_transform(re, im, p16ok, p32ok);

    if (USE_WS) diag_apply_ws(re, im, lane, diag + 2 * DIMQ);
    else        diag_apply_inline(re, im, lane, phis, nullptr, 0.03125f);

#pragma unroll
    for (int j = 0; j < 4; ++j) {
        float4 r4 = make_float4(re[j][0], re[j][1], re[j][2], re[j][3]);
        float4 i4 = make_float4(im[j][0], im[j][1], im[j][2], im[j][3]);
        *(float4*)(orow + j * 256 + lane * 4) = r4;
        *(float4*)(orow + DIMQ + j * 256 + lane * 4) = i4;
    }
}

extern "C" void kernel_launch(void* const* d_in, const int* in_sizes, int n_in,
                              void* d_out, int out_size, void* d_ws, size_t ws_size,
                              hipStream_t stream) {
    const float* x      = (const float*)d_in[0];
    const float* alphas = (const float*)d_in[1];
    const float* betas  = (const float*)d_in[2];
    const float* thetas = (const float*)d_in[3];
    const float* phis   = (const float*)d_in[4];
    float* out = (float*)d_out;

    const int blocks = BATCH_ROWS / 4;  // 4 waves (rows) per 256-thread block

    if (ws_size >= 3 * DIMQ * sizeof(float2)) {
        float2* ws = (float2*)d_ws;
        qdiag_precompute<<<1, DIMQ, 0, stream>>>(alphas, betas, thetas, phis, ws);
        qlayer_kernel<true><<<blocks, 256, 0, stream>>>(x, ws, alphas, betas, thetas, phis, out);
    } else {
        qlayer_kernel<false><<<blocks, 256, 0, stream>>>(x, nullptr, alphas, betas, thetas, phis, out);
    }
}